// Round 5
// baseline (5754.980 us; speedup 1.0000x reference)
//
#include <hip/hip_runtime.h>
#include <math.h>

#define HD 1024
#define BB 256
#define NCAM 15
#define TT 60
#define G3 3072
#define LDW 36      // f32 LDS stride for gi kernel
#define NS 24       // samples per pass, gi kernel

typedef _Float16 f16x8 __attribute__((ext_vector_type(8)));
typedef float f32x4 __attribute__((ext_vector_type(4)));

__device__ __forceinline__ unsigned short f2h(float f) {
    _Float16 h = (_Float16)f;             // v_cvt_f16_f32, RNE
    unsigned short u;
    __builtin_memcpy(&u, &h, 2);
    return u;
}
__device__ __forceinline__ float sigf(float v) { return 1.f / (1.f + expf(-v)); }

// ---------------- grouping ----------------
__global__ void group_kernel(const int* __restrict__ cam,
                             int* __restrict__ off, int* __restrict__ list) {
    __shared__ int cnt[NCAM];
    __shared__ int soff[NCAM + 1];
    int tid = threadIdx.x;
    if (tid < NCAM) cnt[tid] = 0;
    __syncthreads();
    int c = cam[tid];
    int pos = atomicAdd(&cnt[c], 1);
    __syncthreads();
    if (tid == 0) {
        soff[0] = 0;
        for (int i = 0; i < NCAM; ++i) soff[i + 1] = soff[i] + cnt[i];
    }
    __syncthreads();
    list[soff[c] + pos] = tid;
    if (tid <= NCAM) off[tid] = soff[tid];
}

// ---------------- per-camera input projection (f32, unchanged) ----------------
__global__ __launch_bounds__(256) void gi_gemm_kernel(
    const float* __restrict__ W_ih, const float* __restrict__ b_ih,
    const float* __restrict__ b_hh, const float* __restrict__ x,
    const int* __restrict__ off, const int* __restrict__ list,
    float* __restrict__ gi) {
    int c  = blockIdx.x;
    int r0 = blockIdx.y * 96;
    int tid = threadIdx.x;
    int tx = tid & 7, ty = tid >> 3;

    __shared__ __align__(16) float wlds[96 * LDW];
    __shared__ __align__(16) float hlds[NS * LDW];
    __shared__ int slist[NS];

    int base = off[c];
    int nc = off[c + 1] - base;

    for (int s0 = 0; s0 < nc; s0 += NS) {
        __syncthreads();
        if (tid < NS) slist[tid] = (s0 + tid < nc) ? list[base + s0 + tid] : -1;
        __syncthreads();

        float acc[3][3];
#pragma unroll
        for (int g = 0; g < 3; ++g)
#pragma unroll
            for (int q = 0; q < 3; ++q) acc[g][q] = 0.f;

        for (int k0 = 0; k0 < HD; k0 += 32) {
#pragma unroll
            for (int i = 0; i < 3; ++i) {
                int idx = tid + 256 * i;
                int row = idx >> 3, col4 = idx & 7;
                float4 w = *(const float4*)(W_ih +
                    ((size_t)c * G3 + r0 + row) * HD + k0 + col4 * 4);
                *(float4*)(wlds + row * LDW + col4 * 4) = w;
            }
            {
                int s = tid >> 3, col4 = tid & 7;
                if (s < NS) {
                    int b = slist[s];
                    float4 hv = make_float4(0.f, 0.f, 0.f, 0.f);
                    if (b >= 0)
                        hv = *(const float4*)(x + (size_t)b * HD + k0 + col4 * 4);
                    *(float4*)(hlds + s * LDW + col4 * 4) = hv;
                }
            }
            __syncthreads();
#pragma unroll
            for (int kk = 0; kk < 32; kk += 4) {
                float4 w0 = *(const float4*)(wlds + (0 * 32 + ty) * LDW + kk);
                float4 w1 = *(const float4*)(wlds + (1 * 32 + ty) * LDW + kk);
                float4 w2 = *(const float4*)(wlds + (2 * 32 + ty) * LDW + kk);
#pragma unroll
                for (int q = 0; q < 3; ++q) {
                    float4 hv = *(const float4*)(hlds + (tx + 8 * q) * LDW + kk);
                    acc[0][q] += w0.x * hv.x + w0.y * hv.y + w0.z * hv.z + w0.w * hv.w;
                    acc[1][q] += w1.x * hv.x + w1.y * hv.y + w1.z * hv.z + w1.w * hv.w;
                    acc[2][q] += w2.x * hv.x + w2.y * hv.y + w2.z * hv.z + w2.w * hv.w;
                }
            }
            __syncthreads();
        }
#pragma unroll
        for (int q = 0; q < 3; ++q) {
            int b = slist[tx + 8 * q];
            if (b >= 0) {
#pragma unroll
                for (int g = 0; g < 3; ++g) {
                    int R = r0 + g * 32 + ty;
                    float bias = b_ih[c * G3 + R];
                    if (R < 2 * HD) bias += b_hh[c * G3 + R];
                    gi[(size_t)b * G3 + R] = acc[g][q] + bias;
                }
            }
        }
    }
}

// ---------------- W_hh -> fp16 image prep (single plane, unchanged layout) ----------------
__global__ __launch_bounds__(256) void prep_kernel(
    const float* __restrict__ W_hh, unsigned short* __restrict__ Wimg) {
    int c = blockIdx.z, jt = blockIdx.y;
    int lin = blockIdx.x * 256 + threadIdx.x;   // [0, 12288) = 16 iters * 768 chunks
    int it  = lin / 768;
    int rem = lin - it * 768;
    int r = rem >> 3, kcp = rem & 7;
    int gate = r >> 5, jl = r & 31;
    int kc = kcp ^ (r & 7);
    int k = it * 64 + kc * 8;
    const float* src = W_hh + ((size_t)c * G3 + gate * HD + jt * 32 + jl) * HD + k;
    float4 v0 = *(const float4*)src;
    float4 v1 = *(const float4*)(src + 4);
    float v[8] = {v0.x, v0.y, v0.z, v0.w, v1.x, v1.y, v1.z, v1.w};
    unsigned int hp[4];
#pragma unroll
    for (int e = 0; e < 4; ++e) {
        unsigned short h0 = f2h(v[2 * e]), h1 = f2h(v[2 * e + 1]);
        hp[e] = (unsigned)h0 | ((unsigned)h1 << 16);
    }
    unsigned short* dst = Wimg + ((size_t)(c * 32 + jt) * 16 + it) * 6144 + r * 64 + kcp * 8;
    *(uint4*)dst = make_uint4(hp[0], hp[1], hp[2], hp[3]);
}

// ---------------- persistent recurrent kernel: register-resident weights ----------------
// 480 blocks x 128 threads, 0 LDS, ~470 VGPR (384 = weights) -> 1 wave/SIMD,
// 2 blocks/CU, all 480 co-resident (capacity 512). Cross-step sync is
// per-camera: block (c,jt) at step t needs only cam c's 32 blocks from t-1.
// h f32 state lives in registers (lane's (b,j) assignment is step-invariant).
__global__ __launch_bounds__(128, 1) void persist_kernel(
    const unsigned short* __restrict__ Wimg, const float* __restrict__ b_hh,
    const float* __restrict__ gi, const int* __restrict__ off,
    const int* __restrict__ list, const unsigned short* __restrict__ hzero,
    unsigned short* __restrict__ hfA, unsigned short* __restrict__ hfB,
    int* __restrict__ arr, float* __restrict__ out) {
    int c  = blockIdx.x;
    int jt = blockIdx.y;
    int j0 = jt * 32;
    int tid = threadIdx.x;
    int lane = tid & 63;
    int w = tid >> 6;
    int l15 = lane & 15;
    int l4  = lane >> 4;

    // ---- one-time A preload: 96 f16x8 frags/lane (= this block's 96x1024 tile) ----
    f16x8 wreg[96];
    {
        const unsigned short* wbase = Wimg + (size_t)(c * 32 + jt) * 16 * 6144;
#pragma unroll
        for (int it = 0; it < 16; ++it)
#pragma unroll
            for (int kt = 0; kt < 2; ++kt)
#pragma unroll
                for (int g = 0; g < 3; ++g) {
                    int r = g * 32 + w * 16 + l15;
                    int kc = kt * 4 + l4;
                    int kcp = kc ^ (r & 7);
                    wreg[(it * 2 + kt) * 3 + g] =
                        *(const f16x8*)(wbase + (size_t)it * 6144 + r * 64 + kcp * 8);
                }
    }

    int base = off[c];
    int nc = off[c + 1] - base;
    int npass = (nc + 31) >> 5;   // with B=256,C=15 this is 1 (2 supported)

    // persistent f32 hidden state: hreg[pass][q] = h[b][j..j+3]
    f32x4 hreg[2][2];
#pragma unroll
    for (int p = 0; p < 2; ++p)
#pragma unroll
        for (int q = 0; q < 2; ++q) hreg[p][q] = (f32x4){0.f, 0.f, 0.f, 0.f};

    int j = j0 + w * 16 + l4 * 4;
    f32x4 bhn = *(const f32x4*)(b_hh + c * G3 + 2 * HD + j);
    int* arrc = arr + c;

    for (int t = 0; t < TT; ++t) {
        const unsigned short* hf_in = (t & 1) ? hfB : hfA;
        unsigned short*      hf_out = (t & 1) ? hfA : hfB;

        if (t) {
            if (tid == 0) {
                int target = 32 * t;
                int guard = 0;
                while (__hip_atomic_load(arrc, __ATOMIC_RELAXED,
                                         __HIP_MEMORY_SCOPE_AGENT) < target) {
                    __builtin_amdgcn_s_sleep(2);
                    if (++guard > (1 << 20)) break;   // failsafe: never hang
                }
            }
            __syncthreads();
            __threadfence();   // acquire: invalidate stale L1/L2 before reading hf_in
        }

#pragma unroll
        for (int p = 0; p < 2; ++p) {
            if (p < npass) {
                int s0 = p * 32;
                int sv = -1;
                if (lane < 32) sv = (s0 + lane < nc) ? list[base + s0 + lane] : -1;
                int rem = nc - s0;
                int nq = (rem > 16) ? 2 : 1;

                int bidx[2];
                const unsigned short* bq_base[2];
#pragma unroll
                for (int q = 0; q < 2; ++q) {
                    bidx[q] = __shfl(sv, q * 16 + l15);
                    bq_base[q] = (bidx[q] >= 0) ? hf_in + (size_t)bidx[q] * HD : hzero;
                }

                f32x4 acc[3][2];
#pragma unroll
                for (int g = 0; g < 3; ++g)
#pragma unroll
                    for (int q = 0; q < 2; ++q) acc[g][q] = (f32x4){0.f, 0.f, 0.f, 0.f};

#pragma unroll
                for (int it = 0; it < 16; ++it) {
#pragma unroll
                    for (int kt = 0; kt < 2; ++kt) {
                        int koff = it * 64 + (kt * 4 + l4) * 8;
                        f16x8 bq[2];
#pragma unroll
                        for (int q = 0; q < 2; ++q)
                            if (q < nq) bq[q] = *(const f16x8*)(bq_base[q] + koff);
#pragma unroll
                        for (int g = 0; g < 3; ++g) {
#pragma unroll
                            for (int q = 0; q < 2; ++q)
                                if (q < nq)
                                    acc[g][q] = __builtin_amdgcn_mfma_f32_16x16x32_f16(
                                        wreg[(it * 2 + kt) * 3 + g], bq[q], acc[g][q], 0, 0, 0);
                        }
                    }
                }

                // ---- GRU epilogue (f32; h state in registers) ----
#pragma unroll
                for (int q = 0; q < 2; ++q) {
                    if (q < nq) {
                        int b = bidx[q];
                        if (b >= 0) {
                            const float* gib = gi + (size_t)b * G3;
                            f32x4 gr = *(const f32x4*)(gib + j);
                            f32x4 gz = *(const f32x4*)(gib + HD + j);
                            f32x4 gn = *(const f32x4*)(gib + 2 * HD + j);
                            f32x4 hp = hreg[p][q];
                            f32x4 hn;
#pragma unroll
                            for (int e = 0; e < 4; ++e) {
                                float r = sigf(gr[e] + acc[0][q][e]);
                                float z = sigf(gz[e] + acc[1][q][e]);
                                float n = tanhf(gn[e] + r * (acc[2][q][e] + bhn[e]));
                                hn[e] = (1.f - z) * n + z * hp[e];
                                out[((size_t)(b * HD + j + e)) * TT + t] = hn[e];
                            }
                            hreg[p][q] = hn;
                            unsigned int hw[2];
#pragma unroll
                            for (int e = 0; e < 2; ++e) {
                                unsigned short h0 = f2h(hn[2 * e]), h1 = f2h(hn[2 * e + 1]);
                                hw[e] = (unsigned)h0 | ((unsigned)h1 << 16);
                            }
                            *(uint2*)(hf_out + (size_t)b * HD + j) = make_uint2(hw[0], hw[1]);
                        }
                    }
                }
            }
        }

        __threadfence();   // release: drain + push this block's hf stores device-wide
        __syncthreads();
        if (tid == 0)
            __hip_atomic_fetch_add(arrc, 1, __ATOMIC_RELAXED, __HIP_MEMORY_SCOPE_AGENT);
    }
}

extern "C" void kernel_launch(void* const* d_in, const int* in_sizes, int n_in,
                              void* d_out, int out_size, void* d_ws, size_t ws_size,
                              hipStream_t stream) {
    const float* x    = (const float*)d_in[0];
    const int*   cam  = (const int*)d_in[1];
    const float* W_ih = (const float*)d_in[2];
    const float* W_hh = (const float*)d_in[3];
    const float* b_ih = (const float*)d_in[4];
    const float* b_hh = (const float*)d_in[5];
    float* out = (float*)d_out;

    char* ws = (char*)d_ws;
    int*   off   = (int*)ws;                               // 64 B
    int*   list  = (int*)(ws + 64);                        // 1 KB
    int*   arr   = (int*)(ws + 1088);                      // 64 B per-cam arrival counters
    unsigned short* hzero = (unsigned short*)(ws + 2048);  // 2 KB zeros
    float* gi    = (float*)(ws + 4096);                    // 3 MB
    unsigned short* hfA = (unsigned short*)(ws + 3149824); // 512 KB fp16 h plane
    unsigned short* hfB = (unsigned short*)(ws + 3674112); // 512 KB fp16 h plane
    unsigned short* Wimg = (unsigned short*)(ws + 4198400); // 94.4 MB fp16 image

    group_kernel<<<1, 256, 0, stream>>>(cam, off, list);
    gi_gemm_kernel<<<dim3(NCAM, G3 / 96), 256, 0, stream>>>(
        W_ih, b_ih, b_hh, x, off, list, gi);
    prep_kernel<<<dim3(48, 32, NCAM), 256, 0, stream>>>(W_hh, Wimg);
    hipMemsetAsync(hzero, 0, 2048, stream);
    hipMemsetAsync(hfA, 0, (size_t)BB * HD * sizeof(short), stream);
    hipMemsetAsync(arr, 0, 64, stream);   // reset per replay: barrier counters

    persist_kernel<<<dim3(NCAM, HD / 32), 128, 0, stream>>>(
        Wimg, b_hh, gi, off, list, hzero, hfA, hfB, arr, out);
}